// Round 15
// baseline (3997.316 us; speedup 1.0000x reference)
//
#include <hip/hip_runtime.h>
#include <cstdint>
#include <cstddef>

// ---------------------------------------------------------------------------
// GCN2 persistent-kernel (manual barrier) implementation.
// R0 871 ... R10 504 (XCD-pinned slab agg). R12/R13 regressions (agg loop
// frozen at R10 form). R14 502 (bucket+gemm0 merge). ~130us of R14 is
// inter-dispatch gap across 16 serial graph nodes.
// R15 (this): ONE plain-launched persistent kernel, 1024 blocks
// (__launch_bounds__(256,4) -> 4 blocks/CU -> all resident; no coop API,
// which failed in R7). Manual device-scope barrier: per-barrier counters +
// gen word (__hip_atomic agent scope), __threadfence release/acquire for
// cross-XCD L2 writeback/invalidate, __syncthreads drains wave stores first.
// Virgin h/z buffer per layer (no address written-after-read) so stale-L2
// reads are structurally impossible. deg read via agent atomic loads.
// All phase bodies are verbatim R14 kernels. absmax must stay exactly 512.
// ---------------------------------------------------------------------------

#define NN 50000
#define EE 800000

constexpr float ALPHA   = 0.1f;
constexpr float BETA_C  = 0.05406722127027574f;   // log(0.5/9 + 1)

constexpr int GRID = 1024;                        // 4 blocks/CU, all resident
constexpr int NB = (NN + 255) / 256;              // 196 scan chunks
constexpr int HB = (EE + 255) / 256;              // 3125 edge chunks
constexpr int PREP_TOT = 128 * 128 + 6 * 128 * 128 + 64 * 128;   // 122880
constexpr int SLICE = NN / 8;                     // 6250 dst nodes per slice
constexpr int GA = (NN + 63) / 64;                // 782 gemm tiles
constexpr int AGGB = 8 * ((GA + 1) / 2);          // 3128 agg chunks (XCD-pinned)
constexpr size_t SLAB = (size_t)4 * NN * 32;      // u16 per feature buffer

typedef unsigned short u16;
typedef unsigned int   u32;
typedef __attribute__((ext_vector_type(8))) short short8;
typedef __attribute__((ext_vector_type(4))) float f32x4;

__device__ __forceinline__ float bf2f(u16 u) {
    union { float f; u32 i; } c; c.i = ((u32)u) << 16; return c.f;
}
__device__ __forceinline__ u16 f2bf(float f) {          // round-to-nearest-even
    union { float f; u32 i; } c; c.f = f;
    u32 r = c.i + 0x7fffu + ((c.i >> 16) & 1u);
    return (u16)(r >> 16);
}

struct KP {
    const float* x; const int* esrc; const int* edst; const float* ew;
    const float* W0; const float* b0; const float* W1; const float* b1;
    const float* cw; float* out;
    u32* ep4; u16* x0s; u16* hsb; u16* zsb;   // hsb/zsb: 6 slabs each
    u16* w0t; u16* wft; u16* w1t;
    int* deg; int* bsum; int* offs; int* cur; int* bcnt; int* bgen;
};

// ---- device-scope grid barrier: counter k used once, gen monotonic --------
__device__ __forceinline__ void gsync(int* bcnt, int* bgen, int k) {
    __syncthreads();                 // drains each wave's stores into L2
    if (threadIdx.x == 0) {
        __threadfence();             // agent release: L2 writeback
        int prev = __hip_atomic_fetch_add(bcnt + k, 1, __ATOMIC_ACQ_REL,
                                          __HIP_MEMORY_SCOPE_AGENT);
        if (prev == GRID - 1) {
            __hip_atomic_store(bgen, k + 1, __ATOMIC_RELEASE,
                               __HIP_MEMORY_SCOPE_AGENT);
        } else {
            while (__hip_atomic_load(bgen, __ATOMIC_ACQUIRE,
                                     __HIP_MEMORY_SCOPE_AGENT) <= k)
                __builtin_amdgcn_s_sleep(2);
        }
        __threadfence();             // agent acquire: drop stale lines
    }
    __syncthreads();
}

// ---- layer-0 GEMM tile (x fp32 row-major -> relu(x@W0+b0) bf16 slab) ------
__device__ __forceinline__ void gemm0_tile(int t, const float* __restrict__ x,
                                           const u16* __restrict__ w0t,
                                           const float* __restrict__ b0,
                                           u16* __restrict__ x0s) {
    const int lane = threadIdx.x & 63;
    const int wave = threadIdx.x >> 6;
    const int q = lane >> 4;
    const int m16 = lane & 15;
    const int node = t * 64 + wave * 16 + m16;
    const int nload = node < NN ? node : NN - 1;

    short8 zf[4];
    const float* xp = x + (size_t)nload * 128 + q * 8;
#pragma unroll
    for (int s = 0; s < 4; ++s) {
        float4 u0 = *(const float4*)(xp + s * 32);
        float4 u1 = *(const float4*)(xp + s * 32 + 4);
        short8 z;
        z[0] = (short)f2bf(u0.x); z[1] = (short)f2bf(u0.y);
        z[2] = (short)f2bf(u0.z); z[3] = (short)f2bf(u0.w);
        z[4] = (short)f2bf(u1.x); z[5] = (short)f2bf(u1.y);
        z[6] = (short)f2bf(u1.z); z[7] = (short)f2bf(u1.w);
        zf[s] = z;
    }
    f32x4 acc[8];
#pragma unroll
    for (int c = 0; c < 8; ++c) {
        f32x4 a = {0.f, 0.f, 0.f, 0.f};
        const u16* wp = w0t + (size_t)(c * 16 + m16) * 128 + q * 8;
#pragma unroll
        for (int s = 0; s < 4; ++s) {
            short8 wf = *(const short8*)(wp + s * 32);
            a = __builtin_amdgcn_mfma_f32_16x16x32_bf16(wf, zf[s], a, 0, 0, 0);
        }
        acc[c] = a;
    }
    if (node < NN) {
#pragma unroll
        for (int c = 0; c < 8; ++c) {
            const int f0 = c * 16 + q * 4;
            float4 bv = *(const float4*)(b0 + f0);
            float v0 = acc[c][0] + bv.x; v0 = v0 > 0.f ? v0 : 0.f;
            float v1 = acc[c][1] + bv.y; v1 = v1 > 0.f ? v1 : 0.f;
            float v2 = acc[c][2] + bv.z; v2 = v2 > 0.f ? v2 : 0.f;
            float v3 = acc[c][3] + bv.w; v3 = v3 > 0.f ? v3 : 0.f;
            ushort4 o;
            o.x = f2bf(v0); o.y = f2bf(v1); o.z = f2bf(v2); o.w = f2bf(v3);
            *(ushort4*)(x0s + (size_t)(f0 >> 5) * NN * 32
                        + (size_t)node * 32 + (f0 & 31)) = o;
        }
    }
}

// ---- agg chunk (R10-frozen form): slab=(c&7)>>1, 16 nodes x 4 lanes -------
__device__ __forceinline__ void agg_chunk(int c, const int* __restrict__ offs,
                                          const u32* __restrict__ ep,
                                          const u16* __restrict__ hs,
                                          const u16* __restrict__ x0s,
                                          u16* __restrict__ zs) {
    const int s     = (c & 7) >> 1;
    const int chunk = ((c >> 3) << 1) | (c & 1);     // 0..781
    const int lane = threadIdx.x & 63;
    const int wave = threadIdx.x >> 6;
    const int g  = lane >> 2;
    const int f4 = lane & 3;
    const int n  = chunk * 64 + wave * 16 + g;
    const int nc = n < NN ? n : NN - 1;
    const uint4* table = (const uint4*)(hs + (size_t)s * NN * 32);

    const int beg = offs[nc], end = offs[nc + 1];
    float a0 = 0.f, a1 = 0.f, a2 = 0.f, a3 = 0.f;
    float a4 = 0.f, a5 = 0.f, a6 = 0.f, a7 = 0.f;
    int e = beg;
    for (; e + 7 < end; e += 8) {
        u32 r[8]; uint4 v[8];
#pragma unroll
        for (int j = 0; j < 8; ++j) r[j] = ep[e + j];
#pragma unroll
        for (int j = 0; j < 8; ++j)
            v[j] = table[(size_t)(r[j] & 0xffffu) * 4 + f4];
#pragma unroll
        for (int j = 0; j < 8; ++j) {
            float w = bf2f((u16)(r[j] >> 16));
            a0 += w * bf2f((u16)v[j].x);  a1 += w * bf2f((u16)(v[j].x >> 16));
            a2 += w * bf2f((u16)v[j].y);  a3 += w * bf2f((u16)(v[j].y >> 16));
            a4 += w * bf2f((u16)v[j].z);  a5 += w * bf2f((u16)(v[j].z >> 16));
            a6 += w * bf2f((u16)v[j].w);  a7 += w * bf2f((u16)(v[j].w >> 16));
        }
    }
    for (; e < end; ++e) {
        u32 r = ep[e];
        uint4 v = table[(size_t)(r & 0xffffu) * 4 + f4];
        float w = bf2f((u16)(r >> 16));
        a0 += w * bf2f((u16)v.x);  a1 += w * bf2f((u16)(v.x >> 16));
        a2 += w * bf2f((u16)v.y);  a3 += w * bf2f((u16)(v.y >> 16));
        a4 += w * bf2f((u16)v.z);  a5 += w * bf2f((u16)(v.z >> 16));
        a6 += w * bf2f((u16)v.w);  a7 += w * bf2f((u16)(v.w >> 16));
    }
    if (n < NN) {
        const size_t idx = (size_t)s * NN * 4 + (size_t)n * 4 + f4;
        uint4 xv = ((const uint4*)x0s)[idx];
        float z0 = (1.f - ALPHA) * a0 + ALPHA * bf2f((u16)xv.x);
        float z1 = (1.f - ALPHA) * a1 + ALPHA * bf2f((u16)(xv.x >> 16));
        float z2 = (1.f - ALPHA) * a2 + ALPHA * bf2f((u16)xv.y);
        float z3 = (1.f - ALPHA) * a3 + ALPHA * bf2f((u16)(xv.y >> 16));
        float z4 = (1.f - ALPHA) * a4 + ALPHA * bf2f((u16)xv.z);
        float z5 = (1.f - ALPHA) * a5 + ALPHA * bf2f((u16)(xv.z >> 16));
        float z6 = (1.f - ALPHA) * a6 + ALPHA * bf2f((u16)xv.w);
        float z7 = (1.f - ALPHA) * a7 + ALPHA * bf2f((u16)(xv.w >> 16));
        uint4 o;
        o.x = (u32)f2bf(z0) | ((u32)f2bf(z1) << 16);
        o.y = (u32)f2bf(z2) | ((u32)f2bf(z3) << 16);
        o.z = (u32)f2bf(z4) | ((u32)f2bf(z5) << 16);
        o.w = (u32)f2bf(z6) | ((u32)f2bf(z7) << 16);
        ((uint4*)zs)[idx] = o;
    }
}

// ---- conv GEMM tile: h' = relu(z @ Wfold), slab layout --------------------
__device__ __forceinline__ void conv_tile(int t, const u16* __restrict__ z,
                                          const u16* __restrict__ Wt,
                                          u16* __restrict__ hout) {
    const int lane = threadIdx.x & 63;
    const int wave = threadIdx.x >> 6;
    const int q = lane >> 4;
    const int m16 = lane & 15;
    const int node = t * 64 + wave * 16 + m16;
    const int nload = node < NN ? node : NN - 1;

    short8 zf[4];
#pragma unroll
    for (int s = 0; s < 4; ++s)
        zf[s] = *(const short8*)(z + (size_t)s * NN * 32 + (size_t)nload * 32 + q * 8);

    f32x4 acc[8];
#pragma unroll
    for (int c = 0; c < 8; ++c) {
        f32x4 a = {0.f, 0.f, 0.f, 0.f};
        const u16* wp = Wt + (size_t)(c * 16 + m16) * 128 + q * 8;
#pragma unroll
        for (int s = 0; s < 4; ++s) {
            short8 wf = *(const short8*)(wp + s * 32);
            a = __builtin_amdgcn_mfma_f32_16x16x32_bf16(wf, zf[s], a, 0, 0, 0);
        }
        acc[c] = a;
    }
    if (node < NN) {
#pragma unroll
        for (int c = 0; c < 8; ++c) {
            const int f0 = c * 16 + q * 4;
            float v0 = acc[c][0] > 0.f ? acc[c][0] : 0.f;
            float v1 = acc[c][1] > 0.f ? acc[c][1] : 0.f;
            float v2 = acc[c][2] > 0.f ? acc[c][2] : 0.f;
            float v3 = acc[c][3] > 0.f ? acc[c][3] : 0.f;
            ushort4 o;
            o.x = f2bf(v0); o.y = f2bf(v1); o.z = f2bf(v2); o.w = f2bf(v3);
            *(ushort4*)(hout + (size_t)(f0 >> 5) * NN * 32
                        + (size_t)node * 32 + (f0 & 31)) = o;
        }
    }
}

// ---- fused last conv + final projection tile ------------------------------
__device__ __forceinline__ void last_tile(int t, const u16* __restrict__ z,
                                          const u16* __restrict__ wf5,
                                          const u16* __restrict__ w1t,
                                          const float* __restrict__ b1,
                                          float* __restrict__ out) {
    __shared__ __align__(16) u16 hl[4][16][136];
    const int lane = threadIdx.x & 63;
    const int wave = threadIdx.x >> 6;
    const int q = lane >> 4;
    const int m16 = lane & 15;
    const int node = t * 64 + wave * 16 + m16;
    const int nload = node < NN ? node : NN - 1;

    short8 zf[4];
#pragma unroll
    for (int s = 0; s < 4; ++s)
        zf[s] = *(const short8*)(z + (size_t)s * NN * 32 + (size_t)nload * 32 + q * 8);

#pragma unroll
    for (int c = 0; c < 8; ++c) {
        f32x4 a = {0.f, 0.f, 0.f, 0.f};
        const u16* wp = wf5 + (size_t)(c * 16 + m16) * 128 + q * 8;
#pragma unroll
        for (int s = 0; s < 4; ++s) {
            short8 wf = *(const short8*)(wp + s * 32);
            a = __builtin_amdgcn_mfma_f32_16x16x32_bf16(wf, zf[s], a, 0, 0, 0);
        }
        float v0 = a[0] > 0.f ? a[0] : 0.f;
        float v1 = a[1] > 0.f ? a[1] : 0.f;
        float v2 = a[2] > 0.f ? a[2] : 0.f;
        float v3 = a[3] > 0.f ? a[3] : 0.f;
        ushort4 o;
        o.x = f2bf(v0); o.y = f2bf(v1); o.z = f2bf(v2); o.w = f2bf(v3);
        *(ushort4*)&hl[wave][m16][c * 16 + q * 4] = o;
    }
    __syncthreads();

    short8 hf[4];
#pragma unroll
    for (int s = 0; s < 4; ++s)
        hf[s] = *(const short8*)&hl[wave][m16][s * 32 + q * 8];

#pragma unroll
    for (int c = 0; c < 4; ++c) {
        f32x4 a = {0.f, 0.f, 0.f, 0.f};
        const u16* wp = w1t + (size_t)(c * 16 + m16) * 128 + q * 8;
#pragma unroll
        for (int s = 0; s < 4; ++s) {
            short8 wf = *(const short8*)(wp + s * 32);
            a = __builtin_amdgcn_mfma_f32_16x16x32_bf16(wf, hf[s], a, 0, 0, 0);
        }
        if (node < NN) {
            const int f0 = c * 16 + q * 4;
            float4 bv = *(const float4*)(b1 + f0);
            float4 o;
            o.x = a[0] + bv.x; o.y = a[1] + bv.y;
            o.z = a[2] + bv.z; o.w = a[3] + bv.w;
            *(float4*)(out + (size_t)node * 64 + f0) = o;
        }
    }
    __syncthreads();   // protect hl reuse across grid-stride iterations
}

// ---------------------------------------------------------------------------

__global__ __launch_bounds__(256, 4) void k_persist(KP p) {
    const int bid = blockIdx.x;
    const int tid = threadIdx.x;
    int bk = 0;

    // ===== P0: zero deg/bsum + weight prep =====
    for (int i = bid * 256 + tid; i < NN; i += GRID * 256) p.deg[i] = 0;
    if (bid == 0 && tid < NB) p.bsum[tid] = 0;
    for (int i = bid * 256 + tid; i < PREP_TOT; i += GRID * 256) {
        if (i < 16384) {
            int n = i >> 7, k = i & 127;
            p.w0t[i] = f2bf(p.W0[k * 128 + n]);
        } else if (i < 16384 + 6 * 16384) {
            int r = i - 16384;
            int l = r >> 14; int t = r & 16383;
            int n = t >> 7, k = t & 127;
            float v = BETA_C * p.cw[l * 16384 + k * 128 + n]
                      + ((k == n) ? (1.f - BETA_C) : 0.f);
            p.wft[r] = f2bf(v);
        } else {
            int r = i - (16384 + 6 * 16384);
            int n = r >> 7, k = r & 127;
            p.w1t[r] = f2bf(p.W1[k * 64 + n]);
        }
    }
    gsync(p.bcnt, p.bgen, bk++);

    // ===== P1: histogram + layer-0 GEMM =====
    for (int vb = bid; vb < HB + GA; vb += GRID) {
        if (vb < HB) {
            int i = vb * 256 + tid;
            if (i < EE) atomicAdd(&p.deg[p.edst[i]], 1);
        } else {
            gemm0_tile(vb - HB, p.x, p.w0t, p.b0, p.x0s);
        }
    }
    gsync(p.bcnt, p.bgen, bk++);

    // ===== P2: publish-first lookback scan (blocks < NB) =====
    if (bid < NB) {
        __shared__ int sh[256];
        __shared__ int sw[4];
        const int i = bid * 256 + tid;
        int v = (i < NN) ? __hip_atomic_load(&p.deg[i], __ATOMIC_RELAXED,
                                             __HIP_MEMORY_SCOPE_AGENT) : 0;
        sh[tid] = v;
        __syncthreads();
#pragma unroll
        for (int o = 1; o < 256; o <<= 1) {
            int u = (tid >= o) ? sh[tid - o] : 0;
            __syncthreads();
            sh[tid] += u;
            __syncthreads();
        }
        if (tid == 255) atomicExch(&p.bsum[bid], sh[255] + 1);   // publish
        int part = 0;
        for (int t = tid; t < bid; t += 256) {
            int b;
            do { b = atomicAdd(&p.bsum[t], 0); } while (b == 0);
            part += b - 1;
        }
#pragma unroll
        for (int o = 32; o > 0; o >>= 1) part += __shfl_down(part, o);
        if ((tid & 63) == 0) sw[tid >> 6] = part;
        __syncthreads();
        const int base = sw[0] + sw[1] + sw[2] + sw[3];
        const int ex = base + sh[tid] - v;
        if (i < NN) {
            p.offs[i] = ex;
            p.cur[i]  = ex;
            if (i == NN - 1) p.offs[NN] = ex + v;
        }
    }
    gsync(p.bcnt, p.bgen, bk++);

    // ===== P3: 8-way dst-sliced bucket scatter =====
    for (int vb = bid; vb < HB * 8; vb += GRID) {       // GRID%8==0 keeps vb&7
        const int slice = vb & 7;
        const int i = (vb >> 3) * 256 + tid;
        if (i < EE) {
            const int d = p.edst[i];
            const int lo = slice * SLICE;
            if (d >= lo && d < lo + SLICE) {
                int pos = atomicAdd(&p.cur[d], 1);
                p.ep4[pos] = ((u32)f2bf(p.ew[i]) << 16) | (u32)p.esrc[i];
            }
        }
    }
    gsync(p.bcnt, p.bgen, bk++);

    // ===== 6 GCN2 convs (virgin h/z slab per layer) =====
    const u16* hin = p.x0s;
    for (int l = 0; l < 6; ++l) {
        u16* zl = p.zsb + (size_t)l * SLAB;
        for (int c = bid; c < AGGB; c += GRID)          // c&7 invariant
            agg_chunk(c, p.offs, p.ep4, hin, p.x0s, zl);
        gsync(p.bcnt, p.bgen, bk++);

        if (l < 5) {
            u16* hout = p.hsb + (size_t)l * SLAB;
            for (int t = bid; t < GA; t += GRID)
                conv_tile(t, zl, p.wft + (size_t)l * 16384, hout);
            hin = hout;
            gsync(p.bcnt, p.bgen, bk++);
        } else {
            for (int t = bid; t < GA; t += GRID)
                last_tile(t, zl, p.wft + (size_t)5 * 16384, p.w1t, p.b1, p.out);
        }
    }
}

// ---------------------------------------------------------------------------

extern "C" void kernel_launch(void* const* d_in, const int* in_sizes, int n_in,
                              void* d_out, int out_size, void* d_ws, size_t ws_size,
                              hipStream_t stream) {
    KP p;
    p.x    = (const float*)d_in[0];
    p.esrc = (const int*)d_in[1];
    p.edst = (const int*)d_in[2];
    p.ew   = (const float*)d_in[3];
    p.W0   = (const float*)d_in[4];
    p.b0   = (const float*)d_in[5];
    p.W1   = (const float*)d_in[6];
    p.b1   = (const float*)d_in[7];
    p.cw   = (const float*)d_in[8];
    p.out  = (float*)d_out;

    p.ep4 = (u32*)d_ws;                                // EE u32
    p.x0s = (u16*)(p.ep4 + EE);                        // 1 slab
    p.hsb = p.x0s + SLAB;                              // 6 slabs (h, virgin/layer)
    p.zsb = p.hsb + 6 * SLAB;                          // 6 slabs (z, virgin/layer)
    p.w0t = p.zsb + 6 * SLAB;                          // 128*128
    p.wft = p.w0t + 128 * 128;                         // 6*128*128
    p.w1t = p.wft + 6 * 128 * 128;                     // 64*128
    int* ib = (int*)(p.w1t + 64 * 128);
    p.bcnt = ib;                                       // 16 (memset-zeroed)
    p.bgen = ib + 16;                                  // 1  (memset-zeroed)
    p.deg  = ib + 17;                                  // NN (zeroed in P0)
    p.bsum = p.deg + NN;                               // NB (zeroed in P0)
    p.offs = p.bsum + NB;                              // NN+1
    p.cur  = p.offs + NN + 1;                          // NN

    (void)hipMemsetAsync(p.bcnt, 0, 17 * sizeof(int), stream);
    k_persist<<<GRID, 256, 0, stream>>>(p);
}

// Round 16
// 500.975 us; speedup vs baseline: 7.9791x; 7.9791x over previous
//
#include <hip/hip_runtime.h>
#include <cstdint>
#include <cstddef>

// ---------------------------------------------------------------------------
// GCN2: h = relu(x@W0+b0); 6x { agg = scatter_sum(w*h[src] -> dst);
//        z = 0.9*agg + 0.1*x0; h = relu(z @ ((1-b)I + b*Wc)) };
//        out = h@W1 + b1
// R0 871. R1 770. R2 652. R3 592. R4 626 (fused-conv regression). R5/R6 602.
// R7 coop-launch FAILED (API errors in harness). R8 552. R9 546.
// R10 504 (XCD-pinned slab agg — FETCH-verified). R12 519 / R13 547
// regressions (agg loop frozen at R10 scalar 8-unroll form). R14 502
// (bucket+gemm0 merge). R15 3997 REGRESSION: persistent kernel w/ manual
// agent-scope barriers — 1.03GB HBM traffic/call (fences flush L2 on every
// XCD at each of 16 barriers; virgin slabs kill reuse). Multi-dispatch wins
// structurally on this pattern. Persistent/coop approaches CLOSED.
// R16 (this) = R14 verbatim revert — the verified best configuration.
// ---------------------------------------------------------------------------

#define NN 50000
#define EE 800000

constexpr float ALPHA   = 0.1f;
constexpr float BETA_C  = 0.05406722127027574f;   // log(0.5/9 + 1)

constexpr int NB = (NN + 255) / 256;              // 196 scan blocks
constexpr int HB = (EE + 255) / 256;              // 3125 edge chunks
constexpr int PREP_TOT = 128 * 128 + 6 * 128 * 128 + 64 * 128;   // 122880
constexpr int PB = (PREP_TOT + 255) / 256;        // 480 prep blocks
constexpr int SLICE = NN / 8;                     // 6250 dst nodes per slice
constexpr int GA = (NN + 63) / 64;                // 782 gemm blocks / slab chunks
constexpr int AGGB = 8 * ((GA + 1) / 2);          // 3128 agg blocks (XCD-pinned)

typedef unsigned short u16;
typedef unsigned int   u32;
typedef __attribute__((ext_vector_type(8))) short short8;
typedef __attribute__((ext_vector_type(4))) float f32x4;

__device__ __forceinline__ float bf2f(u16 u) {
    union { float f; u32 i; } c; c.i = ((u32)u) << 16; return c.f;
}
__device__ __forceinline__ u16 f2bf(float f) {          // round-to-nearest-even
    union { float f; u32 i; } c; c.f = f;
    u32 r = c.i + 0x7fffu + ((c.i >> 16) & 1u);
    return (u16)(r >> 16);
}

// ------------- merged: histogram (blocks < HB) + weight prep (rest) ---------
__global__ void k_hist_prep(const int* __restrict__ edst, int* __restrict__ deg,
                            const float* __restrict__ W0, const float* __restrict__ cw,
                            const float* __restrict__ W1, u16* __restrict__ w0t,
                            u16* __restrict__ wft, u16* __restrict__ w1t, int E) {
    int b = blockIdx.x;
    if (b < HB) {
        int i = b * 256 + threadIdx.x;
        if (i < E) atomicAdd(&deg[edst[i]], 1);
    } else {
        int i = (b - HB) * 256 + threadIdx.x;
        if (i < 16384) {
            int n = i >> 7, k = i & 127;
            w0t[i] = f2bf(W0[k * 128 + n]);
        } else if (i < 16384 + 6 * 16384) {
            int r = i - 16384;
            int l = r >> 14; int t = r & 16383;
            int n = t >> 7, k = t & 127;
            float v = BETA_C * cw[l * 16384 + k * 128 + n]
                      + ((k == n) ? (1.f - BETA_C) : 0.f);
            wft[r] = f2bf(v);
        } else if (i < PREP_TOT) {
            int r = i - (16384 + 6 * 16384);
            int n = r >> 7, k = r & 127;
            w1t[r] = f2bf(W1[k * 64 + n]);
        }
    }
}

// ---------------- single-dispatch scan: publish-first parallel lookback -----
__global__ __launch_bounds__(256) void k_scan_lb(const int* __restrict__ deg,
                                                 int* __restrict__ bsum,
                                                 int* __restrict__ offs,
                                                 int* __restrict__ cur) {
    __shared__ int sh[256];
    __shared__ int sw[4];
    const int c = blockIdx.x, tid = threadIdx.x;
    const int i = c * 256 + tid;
    int v = (i < NN) ? deg[i] : 0;
    sh[tid] = v;
    __syncthreads();
#pragma unroll
    for (int o = 1; o < 256; o <<= 1) {
        int u = (tid >= o) ? sh[tid - o] : 0;
        __syncthreads();
        sh[tid] += u;
        __syncthreads();
    }
    if (tid == 255) atomicExch(&bsum[c], sh[255] + 1);   // publish (nonzero)
    int part = 0;
    for (int t = tid; t < c; t += 256) {                 // parallel lookback
        int b;
        do { b = atomicAdd(&bsum[t], 0); } while (b == 0);
        part += b - 1;
    }
#pragma unroll
    for (int o = 32; o > 0; o >>= 1) part += __shfl_down(part, o);
    if ((tid & 63) == 0) sw[tid >> 6] = part;
    __syncthreads();
    const int base = sw[0] + sw[1] + sw[2] + sw[3];
    const int ex = base + sh[tid] - v;
    if (i < NN) {
        offs[i] = ex;
        cur[i]  = ex;
        if (i == NN - 1) offs[NN] = ex + v;
    }
}

// ---- layer-0 GEMM tile body (x fp32 row-major -> relu(x@W0+b0) bf16 slab) --
__device__ __forceinline__ void gemm0_tile(int t, const float* __restrict__ x,
                                           const u16* __restrict__ w0t,
                                           const float* __restrict__ b0,
                                           u16* __restrict__ x0s) {
    const int lane = threadIdx.x & 63;
    const int wave = threadIdx.x >> 6;
    const int q = lane >> 4;
    const int m16 = lane & 15;
    const int node = t * 64 + wave * 16 + m16;
    const int nload = node < NN ? node : NN - 1;

    short8 zf[4];
    const float* xp = x + (size_t)nload * 128 + q * 8;
#pragma unroll
    for (int s = 0; s < 4; ++s) {
        float4 u0 = *(const float4*)(xp + s * 32);
        float4 u1 = *(const float4*)(xp + s * 32 + 4);
        short8 z;
        z[0] = (short)f2bf(u0.x); z[1] = (short)f2bf(u0.y);
        z[2] = (short)f2bf(u0.z); z[3] = (short)f2bf(u0.w);
        z[4] = (short)f2bf(u1.x); z[5] = (short)f2bf(u1.y);
        z[6] = (short)f2bf(u1.z); z[7] = (short)f2bf(u1.w);
        zf[s] = z;
    }

    f32x4 acc[8];
#pragma unroll
    for (int c = 0; c < 8; ++c) {
        f32x4 a = {0.f, 0.f, 0.f, 0.f};
        const u16* wp = w0t + (size_t)(c * 16 + m16) * 128 + q * 8;
#pragma unroll
        for (int s = 0; s < 4; ++s) {
            short8 wf = *(const short8*)(wp + s * 32);
            a = __builtin_amdgcn_mfma_f32_16x16x32_bf16(wf, zf[s], a, 0, 0, 0);
        }
        acc[c] = a;
    }

    if (node < NN) {
#pragma unroll
        for (int c = 0; c < 8; ++c) {
            const int f0 = c * 16 + q * 4;
            float4 bv = *(const float4*)(b0 + f0);
            float v0 = acc[c][0] + bv.x; v0 = v0 > 0.f ? v0 : 0.f;
            float v1 = acc[c][1] + bv.y; v1 = v1 > 0.f ? v1 : 0.f;
            float v2 = acc[c][2] + bv.z; v2 = v2 > 0.f ? v2 : 0.f;
            float v3 = acc[c][3] + bv.w; v3 = v3 > 0.f ? v3 : 0.f;
            ushort4 o;
            o.x = f2bf(v0); o.y = f2bf(v1); o.z = f2bf(v2); o.w = f2bf(v3);
            *(ushort4*)(x0s + (size_t)(f0 >> 5) * NN * 32
                        + (size_t)node * 32 + (f0 & 31)) = o;
        }
    }
}

// ------ merged: 8-way dst-sliced bucket scatter + layer-0 GEMM (indep) ------
__global__ __launch_bounds__(256) void k_bucket_g0(const int* __restrict__ src,
                                                   const int* __restrict__ dst,
                                                   const float* __restrict__ w,
                                                   int* __restrict__ cur,
                                                   u32* __restrict__ ep,
                                                   const float* __restrict__ x,
                                                   const u16* __restrict__ w0t,
                                                   const float* __restrict__ b0,
                                                   u16* __restrict__ x0s, int E) {
    const int b = blockIdx.x;
    if (b < HB * 8) {
        const int slice = b & 7;
        const int i = (b >> 3) * 256 + threadIdx.x;
        if (i >= E) return;
        const int d = dst[i];
        const int lo = slice * SLICE;
        if (d >= lo && d < lo + SLICE) {
            int pos = atomicAdd(&cur[d], 1);
            ep[pos] = ((u32)f2bf(w[i]) << 16) | (u32)src[i];
        }
    } else {
        gemm0_tile(b - HB * 8, x, w0t, b0, x0s);
    }
}

// ------- XCD-pinned slab aggregate + z-fold (R10 form — FROZEN) -------------
// Slab layout F[s][n][32] bf16; slab=(bid&7)>>1 -> XCD pair owns one 3.2MB
// slab (L2-resident). Wave = 16 consecutive nodes x 4 lanes (uint4 row part).
__global__ __launch_bounds__(256) void k_agg_z(const int* __restrict__ offs,
                                               const u32* __restrict__ ep,
                                               const u16* __restrict__ hs,
                                               const u16* __restrict__ x0s,
                                               u16* __restrict__ zs) {
    const int bid = blockIdx.x;
    const int s     = (bid & 7) >> 1;
    const int chunk = ((bid >> 3) << 1) | (bid & 1);     // 0..781
    const int lane = threadIdx.x & 63;
    const int wave = threadIdx.x >> 6;
    const int g  = lane >> 2;          // node group 0..15
    const int f4 = lane & 3;           // uint4 index within 64B slab row
    const int n  = chunk * 64 + wave * 16 + g;
    const int nc = n < NN ? n : NN - 1;
    const uint4* table = (const uint4*)(hs + (size_t)s * NN * 32);

    const int beg = offs[nc], end = offs[nc + 1];
    float a0 = 0.f, a1 = 0.f, a2 = 0.f, a3 = 0.f;
    float a4 = 0.f, a5 = 0.f, a6 = 0.f, a7 = 0.f;
    int e = beg;
    for (; e + 7 < end; e += 8) {
        u32 r[8]; uint4 v[8];
#pragma unroll
        for (int j = 0; j < 8; ++j) r[j] = ep[e + j];
#pragma unroll
        for (int j = 0; j < 8; ++j)
            v[j] = table[(size_t)(r[j] & 0xffffu) * 4 + f4];
#pragma unroll
        for (int j = 0; j < 8; ++j) {
            float w = bf2f((u16)(r[j] >> 16));
            a0 += w * bf2f((u16)v[j].x);  a1 += w * bf2f((u16)(v[j].x >> 16));
            a2 += w * bf2f((u16)v[j].y);  a3 += w * bf2f((u16)(v[j].y >> 16));
            a4 += w * bf2f((u16)v[j].z);  a5 += w * bf2f((u16)(v[j].z >> 16));
            a6 += w * bf2f((u16)v[j].w);  a7 += w * bf2f((u16)(v[j].w >> 16));
        }
    }
    for (; e < end; ++e) {
        u32 r = ep[e];
        uint4 v = table[(size_t)(r & 0xffffu) * 4 + f4];
        float w = bf2f((u16)(r >> 16));
        a0 += w * bf2f((u16)v.x);  a1 += w * bf2f((u16)(v.x >> 16));
        a2 += w * bf2f((u16)v.y);  a3 += w * bf2f((u16)(v.y >> 16));
        a4 += w * bf2f((u16)v.z);  a5 += w * bf2f((u16)(v.z >> 16));
        a6 += w * bf2f((u16)v.w);  a7 += w * bf2f((u16)(v.w >> 16));
    }
    if (n < NN) {
        const size_t idx = (size_t)s * NN * 4 + (size_t)n * 4 + f4;   // uint4 units
        uint4 xv = ((const uint4*)x0s)[idx];
        float z0 = (1.f - ALPHA) * a0 + ALPHA * bf2f((u16)xv.x);
        float z1 = (1.f - ALPHA) * a1 + ALPHA * bf2f((u16)(xv.x >> 16));
        float z2 = (1.f - ALPHA) * a2 + ALPHA * bf2f((u16)xv.y);
        float z3 = (1.f - ALPHA) * a3 + ALPHA * bf2f((u16)(xv.y >> 16));
        float z4 = (1.f - ALPHA) * a4 + ALPHA * bf2f((u16)xv.z);
        float z5 = (1.f - ALPHA) * a5 + ALPHA * bf2f((u16)(xv.z >> 16));
        float z6 = (1.f - ALPHA) * a6 + ALPHA * bf2f((u16)xv.w);
        float z7 = (1.f - ALPHA) * a7 + ALPHA * bf2f((u16)(xv.w >> 16));
        uint4 o;
        o.x = (u32)f2bf(z0) | ((u32)f2bf(z1) << 16);
        o.y = (u32)f2bf(z2) | ((u32)f2bf(z3) << 16);
        o.z = (u32)f2bf(z4) | ((u32)f2bf(z5) << 16);
        o.w = (u32)f2bf(z6) | ((u32)f2bf(z7) << 16);
        ((uint4*)zs)[idx] = o;
    }
}

// ---------------- conv MFMA GEMM: h' = relu(z @ Wfold), slab layout ---------
__global__ __launch_bounds__(256) void k_gemm_conv(const u16* __restrict__ z,
                                                   const u16* __restrict__ Wt,
                                                   u16* __restrict__ hout) {
    const int lane = threadIdx.x & 63;
    const int wave = threadIdx.x >> 6;
    const int q = lane >> 4;
    const int m16 = lane & 15;
    const int node = blockIdx.x * 64 + wave * 16 + m16;
    const int nload = node < NN ? node : NN - 1;

    short8 zf[4];
#pragma unroll
    for (int s = 0; s < 4; ++s)
        zf[s] = *(const short8*)(z + (size_t)s * NN * 32 + (size_t)nload * 32 + q * 8);

    f32x4 acc[8];
#pragma unroll
    for (int c = 0; c < 8; ++c) {
        f32x4 a = {0.f, 0.f, 0.f, 0.f};
        const u16* wp = Wt + (size_t)(c * 16 + m16) * 128 + q * 8;
#pragma unroll
        for (int s = 0; s < 4; ++s) {
            short8 wf = *(const short8*)(wp + s * 32);
            a = __builtin_amdgcn_mfma_f32_16x16x32_bf16(wf, zf[s], a, 0, 0, 0);
        }
        acc[c] = a;
    }

    if (node < NN) {
#pragma unroll
        for (int c = 0; c < 8; ++c) {
            const int f0 = c * 16 + q * 4;
            float v0 = acc[c][0] > 0.f ? acc[c][0] : 0.f;
            float v1 = acc[c][1] > 0.f ? acc[c][1] : 0.f;
            float v2 = acc[c][2] > 0.f ? acc[c][2] : 0.f;
            float v3 = acc[c][3] > 0.f ? acc[c][3] : 0.f;
            ushort4 o;
            o.x = f2bf(v0); o.y = f2bf(v1); o.z = f2bf(v2); o.w = f2bf(v3);
            *(ushort4*)(hout + (size_t)(f0 >> 5) * NN * 32
                        + (size_t)node * 32 + (f0 & 31)) = o;
        }
    }
}

// ---------------- fused last conv + final projection ----------------
__global__ __launch_bounds__(256) void k_gemm_last(const u16* __restrict__ z,
                                                   const u16* __restrict__ wf5,
                                                   const u16* __restrict__ w1t,
                                                   const float* __restrict__ b1,
                                                   float* __restrict__ out) {
    __shared__ __align__(16) u16 hl[4][16][136];   // +8 pad: conflict-free
    const int lane = threadIdx.x & 63;
    const int wave = threadIdx.x >> 6;
    const int q = lane >> 4;
    const int m16 = lane & 15;
    const int node = blockIdx.x * 64 + wave * 16 + m16;
    const int nload = node < NN ? node : NN - 1;

    short8 zf[4];
#pragma unroll
    for (int s = 0; s < 4; ++s)
        zf[s] = *(const short8*)(z + (size_t)s * NN * 32 + (size_t)nload * 32 + q * 8);

    // ---- h = relu(z @ Wfold5), bf16 into LDS
#pragma unroll
    for (int c = 0; c < 8; ++c) {
        f32x4 a = {0.f, 0.f, 0.f, 0.f};
        const u16* wp = wf5 + (size_t)(c * 16 + m16) * 128 + q * 8;
#pragma unroll
        for (int s = 0; s < 4; ++s) {
            short8 wf = *(const short8*)(wp + s * 32);
            a = __builtin_amdgcn_mfma_f32_16x16x32_bf16(wf, zf[s], a, 0, 0, 0);
        }
        float v0 = a[0] > 0.f ? a[0] : 0.f;
        float v1 = a[1] > 0.f ? a[1] : 0.f;
        float v2 = a[2] > 0.f ? a[2] : 0.f;
        float v3 = a[3] > 0.f ? a[3] : 0.f;
        ushort4 o;
        o.x = f2bf(v0); o.y = f2bf(v1); o.z = f2bf(v2); o.w = f2bf(v3);
        *(ushort4*)&hl[wave][m16][c * 16 + q * 4] = o;
    }
    __syncthreads();

    // ---- out = h @ W1 + b1
    short8 hf[4];
#pragma unroll
    for (int s = 0; s < 4; ++s)
        hf[s] = *(const short8*)&hl[wave][m16][s * 32 + q * 8];

#pragma unroll
    for (int c = 0; c < 4; ++c) {
        f32x4 a = {0.f, 0.f, 0.f, 0.f};
        const u16* wp = w1t + (size_t)(c * 16 + m16) * 128 + q * 8;
#pragma unroll
        for (int s = 0; s < 4; ++s) {
            short8 wf = *(const short8*)(wp + s * 32);
            a = __builtin_amdgcn_mfma_f32_16x16x32_bf16(wf, hf[s], a, 0, 0, 0);
        }
        if (node < NN) {
            const int f0 = c * 16 + q * 4;
            float4 bv = *(const float4*)(b1 + f0);
            float4 o;
            o.x = a[0] + bv.x; o.y = a[1] + bv.y;
            o.z = a[2] + bv.z; o.w = a[3] + bv.w;
            *(float4*)(out + (size_t)node * 64 + f0) = o;
        }
    }
}

// ---------------------------------------------------------------------------

extern "C" void kernel_launch(void* const* d_in, const int* in_sizes, int n_in,
                              void* d_out, int out_size, void* d_ws, size_t ws_size,
                              hipStream_t stream) {
    const float* x    = (const float*)d_in[0];
    const int*   esrc = (const int*)d_in[1];
    const int*   edst = (const int*)d_in[2];
    const float* ew   = (const float*)d_in[3];
    const float* W0   = (const float*)d_in[4];
    const float* b0   = (const float*)d_in[5];
    const float* W1   = (const float*)d_in[6];
    const float* b1   = (const float*)d_in[7];
    const float* cw   = (const float*)d_in[8];
    float* out = (float*)d_out;

    // workspace layout; slab buffers are [4][NN][32] bf16
    u32* ep4 = (u32*)d_ws;
    u16* x0s = (u16*)(ep4 + EE);
    u16* hb1 = x0s + (size_t)4 * NN * 32;
    u16* hb2 = hb1 + (size_t)4 * NN * 32;
    u16* zsb = hb2 + (size_t)4 * NN * 32;
    u16* w0t = zsb + (size_t)4 * NN * 32;
    u16* wft = w0t + 128 * 128;
    u16* w1t = wft + 6 * 128 * 128;
    int* deg = (int*)(w1t + 64 * 128);
    int* bsum = deg + NN;
    int* offs = bsum + NB;
    int* cur = offs + NN + 1;

    // ---- CSR build + weight prep; bucket merged with layer-0 GEMM
    (void)hipMemsetAsync(deg, 0, (size_t)(NN + NB) * sizeof(int), stream);
    k_hist_prep<<<HB + PB, 256, 0, stream>>>(edst, deg, W0, cw, W1, w0t, wft, w1t, EE);
    k_scan_lb<<<NB, 256, 0, stream>>>(deg, bsum, offs, cur);
    k_bucket_g0<<<HB * 8 + GA, 256, 0, stream>>>(esrc, edst, ew, cur, ep4,
                                                 x, w0t, b0, x0s, EE);

    // ---- convs 0..4: z = 0.9*agg(h) + 0.1*x0 ; h' = relu(z @ Wfold)
    const u16* hin = x0s;
    u16* houts[5] = {hb1, hb2, hb1, hb2, hb1};
    for (int i = 0; i < 5; ++i) {
        k_agg_z<<<AGGB, 256, 0, stream>>>(offs, ep4, hin, x0s, zsb);
        k_gemm_conv<<<GA, 256, 0, stream>>>(zsb, wft + (size_t)i * 16384, houts[i]);
        hin = houts[i];
    }

    // ---- conv 5 fused with final projection
    k_agg_z<<<AGGB, 256, 0, stream>>>(offs, ep4, hin, x0s, zsb);
    k_gemm_last<<<GA, 256, 0, stream>>>(zsb, wft + (size_t)5 * 16384, w1t, b1, out);
}